// Round 1
// baseline (46.552 us; speedup 1.0000x reference)
//
#include <hip/hip_runtime.h>

#define DIM 256

__global__ __launch_bounds__(256) void splitpool_kernel(
    const float* __restrict__ x,
    const int* __restrict__ chunk_size,
    const int* __restrict__ n_peaks,
    float* __restrict__ out,
    int B, int L, int P)
{
    const int blk = blockIdx.x;
    const int b   = blk / P;
    const int j   = blk % P;
    const int tid = threadIdx.x;

    float4* out4 = (float4*)(out + (size_t)blk * DIM);

    const int np = n_peaks[b];
    if (j >= np) {
        // invalid slot: write zeros (d_out is poisoned, not re-poisoned between replays)
        if (tid < DIM / 4) out4[tid] = make_float4(0.f, 0.f, 0.f, 0.f);
        return;
    }

    // first chunk index of sample b: starts[b] = sum_{b'<b} (n_peaks[b'] + 1)
    int c0 = 0;
    for (int bb = 0; bb < b; ++bb) c0 += n_peaks[bb] + 1;

    // prefix = sum_{k<j} chunk_size[c0+k]  (block-wide reduce, <=391 values, L2-hot)
    __shared__ int ired[256];
    int partial = 0;
    for (int k = tid; k < j; k += 256) partial += chunk_size[c0 + k];
    ired[tid] = partial;
    __syncthreads();
    #pragma unroll
    for (int s = 128; s > 0; s >>= 1) {
        if (tid < s) ired[tid] += ired[tid + s];
        __syncthreads();
    }
    const int prefix = ired[0];
    const int nrows  = chunk_size[c0 + j];
    const size_t row0 = (size_t)b * (size_t)L + (size_t)prefix;

    // 4 waves, each takes every 4th row; lane l owns float4 of dims [4l, 4l+4)
    const int wave = tid >> 6;
    const int lane = tid & 63;
    const float4* xp = (const float4*)(x + row0 * DIM) + lane;  // row = 64 float4

    float4 acc = make_float4(0.f, 0.f, 0.f, 0.f);
    for (int r = wave; r < nrows; r += 4) {
        float4 v = xp[(size_t)r * (DIM / 4)];
        acc.x += v.x; acc.y += v.y; acc.z += v.z; acc.w += v.w;
    }

    // cross-wave reduction in LDS
    __shared__ float4 fred[256];
    fred[tid] = acc;
    __syncthreads();
    if (tid < 64) {
        float4 a  = fred[tid];
        float4 b1 = fred[tid + 64];
        float4 c  = fred[tid + 128];
        float4 d  = fred[tid + 192];
        a.x += b1.x + c.x + d.x;
        a.y += b1.y + c.y + d.y;
        a.z += b1.z + c.z + d.z;
        a.w += b1.w + c.w + d.w;
        out4[tid] = a;
    }
}

extern "C" void kernel_launch(void* const* d_in, const int* in_sizes, int n_in,
                              void* d_out, int out_size, void* d_ws, size_t ws_size,
                              hipStream_t stream) {
    const float* x  = (const float*)d_in[0];
    const int*   cs = (const int*)d_in[1];
    const int*   np = (const int*)d_in[2];
    float*       out = (float*)d_out;

    const int B = in_sizes[2];                 // n_peaks has one entry per sample
    const int P = out_size / (B * DIM);        // max_n_peaks
    const int L = in_sizes[0] / (B * DIM);     // sequence length

    dim3 grid(B * P);
    splitpool_kernel<<<grid, 256, 0, stream>>>(x, cs, np, out, B, L, P);
}